// Round 10
// baseline (158.396 us; speedup 1.0000x reference)
//
#include <hip/hip_runtime.h>

#define N_NODES 50000
#define N_EDGES 1600000
#define IN_DIM 6
#define H 64

#define BSHIFT 7               // bucket = dst >> 7  (128 nodes per bucket)
#define BNODES 128
#define NBUCKET 391            // ceil(50000 / 128)
#define BCAP 4736              // bucket capacity: mean 4096, sd ~64 -> +10 sd
#define NCHUNK 500             // edge chunks
#define EPB 3200               // edges per chunk (500*3200 = 1.6M exact)

#define L2PAD 72               // padded LDS row stride (bf16) = 144B

// bf16 helpers (storage-only; all math in fp32)
__device__ __forceinline__ float bf2f(unsigned short u) {
    return __uint_as_float(((unsigned int)u) << 16);
}
__device__ __forceinline__ unsigned short f2bf(float f) {
    unsigned int u = __float_as_uint(f);
    u += 0x7fffu + ((u >> 16) & 1u);   // round-to-nearest-even
    return (unsigned short)(u >> 16);
}

// ---------------------------------------------------------------------------
// Pass A: stage chunk edges in LDS, LDS histogram over 391 buckets, reserve
// bucket ranges via one global atomicAdd per (block,bucket), scatter from LDS.
// Extra block NCHUNK does W2 transpose prep + zeroes z's dummy row.
// ---------------------------------------------------------------------------
__global__ __launch_bounds__(256) void scatter_bucketed(
        const int* __restrict__ ei,
        int* __restrict__ gcur,
        unsigned int* __restrict__ ebin,
        const float* __restrict__ W2l,
        const float* __restrict__ W2r,
        unsigned short* __restrict__ Wlt,
        unsigned short* __restrict__ Wrt,
        unsigned short* __restrict__ z) {
    int t = threadIdx.x;
    if (blockIdx.x == NCHUNK) {                // w2prep + z zero-row block
        for (int i = t; i < H * H; i += 256) {
            int k = i >> 6, f = i & 63;
            Wlt[f * H + k] = f2bf(W2l[i]);
            Wrt[f * H + k] = f2bf(W2r[i]);
        }
        if (t < H) z[(size_t)N_NODES * H + t] = 0;
        return;
    }
    __shared__ unsigned int sedge[EPB];        // 12.8 KB staged edges
    __shared__ int hist[NBUCKET];
    __shared__ int cur[NBUCKET];
    for (int i = t; i < NBUCKET; i += 256) hist[i] = 0;
    __syncthreads();
    int e0 = blockIdx.x * EPB;
    const int4* s4 = (const int4*)(ei + e0);
    const int4* d4 = (const int4*)(ei + N_EDGES + e0);
    for (int k = t; k * 4 < EPB; k += 256) {
        int4 sv = s4[k];
        int4 dv = d4[k];
        sedge[k * 4 + 0] = ((unsigned)sv.x << 16) | (unsigned)dv.x;
        sedge[k * 4 + 1] = ((unsigned)sv.y << 16) | (unsigned)dv.y;
        sedge[k * 4 + 2] = ((unsigned)sv.z << 16) | (unsigned)dv.z;
        sedge[k * 4 + 3] = ((unsigned)sv.w << 16) | (unsigned)dv.w;
        atomicAdd(&hist[dv.x >> BSHIFT], 1);
        atomicAdd(&hist[dv.y >> BSHIFT], 1);
        atomicAdd(&hist[dv.z >> BSHIFT], 1);
        atomicAdd(&hist[dv.w >> BSHIFT], 1);
    }
    __syncthreads();
    for (int i = t; i < NBUCKET; i += 256)
        cur[i] = atomicAdd(&gcur[i], hist[i]);
    __syncthreads();
    for (int k = t; k * 4 < EPB; k += 256) {
#pragma unroll
        for (int j = 0; j < 4; j++) {
            unsigned int p = sedge[k * 4 + j];
            int b = (int)(p & 0xffffu) >> BSHIFT;
            int pos = atomicAdd(&cur[b], 1);
            if (pos < BCAP) ebin[(size_t)b * BCAP + pos] = p;
        }
    }
}

// ---------------------------------------------------------------------------
// Pass B + Layer 1 fused: one block (512 thr) per 128-node bucket.
//   1. LDS counting sort of the bucket's ~4096 edges -> ssrc, rowpair, esrc
//   2. layer-1 x-gather from LDS ssrc (4 threads per node)
//   3. linear: feat-per-thread, W1 in registers, broadcast float4 LDS reads
// Static LDS ~34 KB (raw region aliased by smx/spart after the sort).
// ---------------------------------------------------------------------------
__global__ __launch_bounds__(512) void bucket_layer1(
        const unsigned int* __restrict__ ebin,
        const int* __restrict__ gcur,
        const float* __restrict__ x,
        const float* __restrict__ W1l,
        const float* __restrict__ b1,
        const float* __restrict__ W1r,
        int2* __restrict__ rowpair,
        unsigned short* __restrict__ esrc,
        unsigned short* __restrict__ z) {
    __shared__ __attribute__((aligned(16))) int raw[BCAP];   // 18944 B (aliased)
    __shared__ unsigned short ssrc[BCAP];                    // 9472 B
    __shared__ int sdeg[BNODES];
    __shared__ int sstart[BNODES];
    __shared__ int scur[BNODES];
    __shared__ int wsum[2];
    __shared__ float sW1l[IN_DIM * H];
    __shared__ float sW1r[IN_DIM * H];
    float* smx   = (float*)raw;            // [128][16]: mean 0..5, self 6..11
    float* spart = (float*)raw + 2048;     // [3][128][6] partials (quarters 1-3)

    int t = threadIdx.x;
    int lane = t & 63, w = t >> 6;
    int b = blockIdx.x;
    int base = b << BSHIFT;
    int nn = min(BNODES, N_NODES - base);  // last bucket: 80 nodes
    int ebase = b * BCAP;
    int cnt = min(gcur[b], BCAP);

    if (t < BNODES) sdeg[t] = 0;
    if (t < IN_DIM * H) { sW1l[t] = W1l[t]; sW1r[t] = W1r[t]; }
    for (int i = t; i < cnt; i += 512) raw[i] = (int)ebin[ebase + i];
    __syncthreads();
    for (int i = t; i < cnt; i += 512) atomicAdd(&sdeg[raw[i] & (BNODES - 1)], 1);
    __syncthreads();
    int v = 0, s = 0;
    if (t < BNODES) {                      // waves 0..1: scan of 128 bins
        v = sdeg[t]; s = v;
#pragma unroll
        for (int off = 1; off < 64; off <<= 1) {
            int u = __shfl_up(s, off);
            if (lane >= off) s += u;
        }
        if (lane == 63) wsum[w] = s;
    }
    __syncthreads();
    if (t < BNODES) {
        int woff = (w == 1) ? wsum[0] : 0;
        int excl = s - v + woff;           // bucket-local exclusive prefix
        sstart[t] = excl;
        scur[t] = excl;
        if (t < nn) rowpair[base + t] = make_int2(ebase + excl, ebase + excl + v);
    }
    __syncthreads();
    for (int i = t; i < cnt; i += 512) {   // in-LDS scatter (sort)
        int p = raw[i];
        int pos = atomicAdd(&scur[p & (BNODES - 1)], 1);
        ssrc[pos] = (unsigned short)((unsigned)p >> 16);
    }
    __syncthreads();
    // raw[] dead from here on: smx/spart alias it.
    for (int i = t; i < cnt; i += 512)     // coalesced esrc write (for layer2)
        esrc[ebase + i] = ssrc[i];
    for (int i = t; i < nn * IN_DIM; i += 512) {   // stage self x rows (contig)
        int node = i / 6, k = i - node * 6;
        smx[node * 16 + 6 + k] = x[(size_t)base * IN_DIM + i];
    }

    // ---- layer-1 gather: 4 threads per node, each edge read once ----
    int node = t & (BNODES - 1), q = t >> BSHIFT;   // q in 0..3
    float a0 = 0.f, a1 = 0.f, a2 = 0.f, a3 = 0.f, a4 = 0.f, a5 = 0.f;
    int deg = 0, st = 0;
    if (node < nn) { deg = sdeg[node]; st = sstart[node]; }
    for (int i = st + q; i < st + deg; i += 4) {
        int src = ssrc[i];
        const float2* xs = (const float2*)(x + (size_t)src * IN_DIM);
        float2 p0 = xs[0], p1 = xs[1], p2 = xs[2];
        a0 += p0.x; a1 += p0.y; a2 += p1.x;
        a3 += p1.y; a4 += p2.x; a5 += p2.y;
    }
    if (q > 0 && node < nn) {
        float* sp = &spart[(q - 1) * (BNODES * 6) + node * 6];
        sp[0] = a0; sp[1] = a1; sp[2] = a2; sp[3] = a3; sp[4] = a4; sp[5] = a5;
    }
    __syncthreads();
    if (q == 0 && node < nn) {
        float inv = 1.0f / fmaxf((float)deg, 1.0f);
        const float* p1p = &spart[0 * (BNODES * 6) + node * 6];
        const float* p2p = &spart[1 * (BNODES * 6) + node * 6];
        const float* p3p = &spart[2 * (BNODES * 6) + node * 6];
        smx[node * 16 + 0] = (a0 + p1p[0] + p2p[0] + p3p[0]) * inv;
        smx[node * 16 + 1] = (a1 + p1p[1] + p2p[1] + p3p[1]) * inv;
        smx[node * 16 + 2] = (a2 + p1p[2] + p2p[2] + p3p[2]) * inv;
        smx[node * 16 + 3] = (a3 + p1p[3] + p2p[3] + p3p[3]) * inv;
        smx[node * 16 + 4] = (a4 + p1p[4] + p2p[4] + p3p[4]) * inv;
        smx[node * 16 + 5] = (a5 + p1p[5] + p2p[5] + p3p[5]) * inv;
    }
    __syncthreads();

    // ---- layer-1 linear: feat-per-thread, weights in registers ----
    int feat = t & 63, ng = t >> 6;        // 8 node-groups
    float wl[IN_DIM], wr[IN_DIM];
#pragma unroll
    for (int k = 0; k < IN_DIM; k++) { wl[k] = sW1l[k * H + feat]; wr[k] = sW1r[k * H + feat]; }
    float bias = b1[feat];
    for (int nb = ng; nb < nn; nb += 8) {
        const float4* row = (const float4*)&smx[nb * 16];  // broadcast reads
        float4 r0 = row[0], r1 = row[1], r2 = row[2];
        float acc = bias;
        acc += r0.x * wl[0] + r0.y * wl[1] + r0.z * wl[2]
             + r0.w * wl[3] + r1.x * wl[4] + r1.y * wl[5];
        acc += r1.z * wr[0] + r1.w * wr[1] + r2.x * wr[2]
             + r2.y * wr[3] + r2.z * wr[4] + r2.w * wr[5];
        z[(size_t)(base + nb) * H + feat] = f2bf(fmaxf(acc, 0.0f));
    }
}

// ---------------------------------------------------------------------------
// Layer 2, MFMA epilogue: 512 thr / 8 waves / 32 nodes per block (grid 1563,
// LDS 27.6KB -> 4 blocks/CU = 32 waves/CU).  Gather: wave w -> nodes
// w*4..w*4+3 (proven 4-group ushort4 pattern).  MFMA: wave w -> node-halves
// (w>>2) x feats [16*(w&3), +16): one 16x16 tile per wave.
// ---------------------------------------------------------------------------
__global__ __launch_bounds__(512) void layer2_mfma(
        const unsigned short* __restrict__ zin,
        const int2* __restrict__ rowpair,
        const unsigned short* __restrict__ esrc,
        const unsigned short* __restrict__ Wlt,
        const float* __restrict__ b2,
        const unsigned short* __restrict__ Wrt,
        float* __restrict__ out) {
    typedef short bf16x8 __attribute__((ext_vector_type(8)));
    typedef float f32x4 __attribute__((ext_vector_type(4)));
    __shared__ __attribute__((aligned(16))) unsigned short smean[32 * L2PAD];
    __shared__ __attribute__((aligned(16))) unsigned short szl[32 * L2PAD];
    __shared__ __attribute__((aligned(16))) unsigned short sWl[64 * L2PAD];
    __shared__ __attribute__((aligned(16))) unsigned short sWr[64 * L2PAD];

    int t = threadIdx.x;
    int w = t >> 6, lane = t & 63;
    int g = lane >> 4, lg = lane & 15;
    int n0 = blockIdx.x * 32;

    // stage pre-transposed bf16 weights (k-consecutive: conflict-free)
    {
        const ushort4* wl4 = (const ushort4*)Wlt;
        const ushort4* wr4 = (const ushort4*)Wrt;
        for (int qi = t; qi < H * H / 4; qi += 512) {
            int f = qi >> 4, kq = qi & 15;
            *(ushort4*)&sWl[f * L2PAD + kq * 4] = wl4[qi];
            *(ushort4*)&sWr[f * L2PAD + kq * 4] = wr4[qi];
        }
    }

    // ---- gather phase: wave w -> nodes w*4 .. w*4+3 ----
    for (int q = 0; q < 4; q++) {
        int ln = w * 4 + q;
        int n = n0 + ln;
        bool valid = (n < N_NODES);
        int r0 = 0, r1 = 0;
        if (valid) { int2 rp = rowpair[n]; r0 = rp.x; r1 = rp.y; }
        float4 acc = make_float4(0.f, 0.f, 0.f, 0.f);
        for (int base = r0; base < r1; base += 64) {
            int ii = base + lane;
            int idx = (ii < r1) ? (int)esrc[ii] : N_NODES;   // zero row
            int rem = r1 - base;                             // wave-uniform
#pragma unroll 1
            for (int c = 0; c < 64; c += 16) {
                if (c >= rem) break;                         // wave-uniform
#pragma unroll
                for (int tt = 0; tt < 4; tt++) {
                    int j = c + tt * 4 + g;
                    int s = __shfl(idx, j);
                    const ushort4* zr = (const ushort4*)(zin + (size_t)s * H);
                    ushort4 vv = zr[lg];
                    acc.x += bf2f(vv.x); acc.y += bf2f(vv.y);
                    acc.z += bf2f(vv.z); acc.w += bf2f(vv.w);
                }
            }
        }
#pragma unroll
        for (int off = 16; off < 64; off <<= 1) {
            acc.x += __shfl_xor(acc.x, off);
            acc.y += __shfl_xor(acc.y, off);
            acc.z += __shfl_xor(acc.z, off);
            acc.w += __shfl_xor(acc.w, off);
        }
        float inv = 1.0f / fmaxf((float)(r1 - r0), 1.0f);
        if (g == 0) {
            ushort4 mb;
            mb.x = f2bf(acc.x * inv); mb.y = f2bf(acc.y * inv);
            mb.z = f2bf(acc.z * inv); mb.w = f2bf(acc.w * inv);
            *(ushort4*)&smean[ln * L2PAD + lg * 4] = mb;
        }
        int nz = valid ? n : N_NODES;                        // zero row for pad
        szl[ln * L2PAD + lane] = zin[(size_t)nz * H + lane];
    }
    __syncthreads();

    // ---- MFMA phase: wave w -> nodes [16*(w>>2), +16) x feats [16*(w&3), +16)
    int nb = w >> 2, fb = w & 3;
    f32x4 acc = {0.f, 0.f, 0.f, 0.f};
#pragma unroll
    for (int ks = 0; ks < 2; ks++) {
        int ko = ks * 32 + g * 8;
        bf16x8 aM = *(const bf16x8*)&smean[(nb * 16 + lg) * L2PAD + ko];
        bf16x8 aZ = *(const bf16x8*)&szl[(nb * 16 + lg) * L2PAD + ko];
        bf16x8 bL = *(const bf16x8*)&sWl[(fb * 16 + lg) * L2PAD + ko];
        bf16x8 bR = *(const bf16x8*)&sWr[(fb * 16 + lg) * L2PAD + ko];
        acc = __builtin_amdgcn_mfma_f32_16x16x32_bf16(aM, bL, acc, 0, 0, 0);
        acc = __builtin_amdgcn_mfma_f32_16x16x32_bf16(aZ, bR, acc, 0, 0, 0);
    }
    float bias = b2[fb * 16 + lg];
#pragma unroll
    for (int r = 0; r < 4; r++) {
        int node = n0 + nb * 16 + g * 4 + r;
        if (node < N_NODES)
            out[(size_t)node * H + fb * 16 + lg] = acc[r] + bias;
    }
}

// ---------------------------------------------------------------------------
extern "C" void kernel_launch(void* const* d_in, const int* in_sizes, int n_in,
                              void* d_out, int out_size, void* d_ws, size_t ws_size,
                              hipStream_t stream) {
    const float* x   = (const float*)d_in[0];
    const int*   ei  = (const int*)d_in[1];   // [2, N_EDGES]
    const float* W1l = (const float*)d_in[2];
    const float* b1  = (const float*)d_in[3];
    const float* W1r = (const float*)d_in[4];
    const float* W2l = (const float*)d_in[5];
    const float* b2  = (const float*)d_in[6];
    const float* W2r = (const float*)d_in[7];
    float* out = (float*)d_out;

    // Workspace layout (keeps 16B alignment for ebin/esrc/z/weights):
    int* gcur = (int*)d_ws;                              // 391 (+pad to 400)
    int2* rowpair = (int2*)(gcur + 400);                 // 50000 int2
    unsigned int*   ebin = (unsigned int*)(rowpair + N_NODES);  // 391*4736 u32
    unsigned short* esrc = (unsigned short*)(ebin + (size_t)NBUCKET * BCAP);
    unsigned short* z    = esrc + (size_t)NBUCKET * BCAP;  // (N_NODES+1)*H bf16
    unsigned short* Wlt  = z + (size_t)(N_NODES + 1) * H;  // 4096 bf16
    unsigned short* Wrt  = Wlt + H * H;                    // 4096 bf16

    hipMemsetAsync(gcur, 0, NBUCKET * sizeof(int), stream);

    // CSR build (chunked scatter) + fused bucket-sort/layer1, then layer2
    scatter_bucketed<<<NCHUNK + 1, 256, 0, stream>>>(ei, gcur, ebin,
                                                     W2l, W2r, Wlt, Wrt, z);
    bucket_layer1<<<NBUCKET, 512, 0, stream>>>(ebin, gcur, x, W1l, b1, W1r,
                                               rowpair, esrc, z);
    layer2_mfma<<<(N_NODES + 31) / 32, 512, 0, stream>>>(z, rowpair, esrc,
                                                         Wlt, b2, Wrt, out);
}

// Round 11
// 152.869 us; speedup vs baseline: 1.0362x; 1.0362x over previous
//
#include <hip/hip_runtime.h>

#define N_NODES 50000
#define N_EDGES 1600000
#define IN_DIM 6
#define H 64

#define NBUCKET 196            // dst >> 8  (256 nodes per bucket)
#define NBLK 196               // edge chunks
#define EPB 8192               // edges per chunk (196*8192 >= 1.6M)
#define BCAP 9216              // bucket capacity: mean 8163, sd ~90 -> +11.6 sd

#define L2PAD 72               // padded LDS row stride (bf16) = 144B

// bf16 helpers (storage-only; all math in fp32)
__device__ __forceinline__ float bf2f(unsigned short u) {
    return __uint_as_float(((unsigned int)u) << 16);
}
__device__ __forceinline__ unsigned short f2bf(float f) {
    unsigned int u = __float_as_uint(f);
    u += 0x7fffu + ((u >> 16) & 1u);   // round-to-nearest-even
    return (unsigned short)(u >> 16);
}

// ---------------------------------------------------------------------------
// Pass A (fused): stage edges in LDS, LDS histogram, reserve bucket ranges
// via ONE global atomicAdd per (block,bucket), scatter from LDS.
// 196 chunks of 8192: per-(block,bucket) ebin runs ~42 edges (~168B) — keeps
// scatter writes mostly-full-line (round-10's 500x391 split broke this).
// Extra block NBLK does the W2 transpose prep + zeroes z's dummy row.
// ---------------------------------------------------------------------------
__global__ __launch_bounds__(256) void scatter_bucketed(
        const int* __restrict__ ei,
        int* __restrict__ gcur,
        unsigned int* __restrict__ ebin,
        const float* __restrict__ W2l,
        const float* __restrict__ W2r,
        unsigned short* __restrict__ Wlt,
        unsigned short* __restrict__ Wrt,
        unsigned short* __restrict__ z) {
    int t = threadIdx.x;
    if (blockIdx.x == NBLK) {                  // w2prep + z zero-row block
        for (int i = t; i < H * H; i += 256) {
            int k = i >> 6, f = i & 63;
            Wlt[f * H + k] = f2bf(W2l[i]);
            Wrt[f * H + k] = f2bf(W2r[i]);
        }
        if (t < H) z[(size_t)N_NODES * H + t] = 0;
        return;
    }
    __shared__ unsigned int sedge[EPB];        // 32 KB staged edges
    __shared__ int hist[NBUCKET];
    __shared__ int cur[NBUCKET];
    for (int i = t; i < NBUCKET; i += 256) hist[i] = 0;
    __syncthreads();
    int e0 = blockIdx.x * EPB;
    int cnt = min(EPB, N_EDGES - e0);          // multiple of 4
    const int4* s4 = (const int4*)(ei + e0);
    const int4* d4 = (const int4*)(ei + N_EDGES + e0);
    for (int k = t; k * 4 < cnt; k += 256) {
        int4 sv = s4[k];
        int4 dv = d4[k];
        sedge[k * 4 + 0] = ((unsigned)sv.x << 16) | (unsigned)dv.x;
        sedge[k * 4 + 1] = ((unsigned)sv.y << 16) | (unsigned)dv.y;
        sedge[k * 4 + 2] = ((unsigned)sv.z << 16) | (unsigned)dv.z;
        sedge[k * 4 + 3] = ((unsigned)sv.w << 16) | (unsigned)dv.w;
        atomicAdd(&hist[dv.x >> 8], 1);
        atomicAdd(&hist[dv.y >> 8], 1);
        atomicAdd(&hist[dv.z >> 8], 1);
        atomicAdd(&hist[dv.w >> 8], 1);
    }
    __syncthreads();
    for (int i = t; i < NBUCKET; i += 256)
        cur[i] = atomicAdd(&gcur[i], hist[i]);
    __syncthreads();
    for (int k = t; k * 4 < cnt; k += 256) {
#pragma unroll
        for (int j = 0; j < 4; j++) {
            unsigned int p = sedge[k * 4 + j];
            int b = (int)(p & 0xffffu) >> 8;
            int pos = atomicAdd(&cur[b], 1);
            if (pos < BCAP) ebin[(size_t)b * BCAP + pos] = p;
        }
    }
}

// ---------------------------------------------------------------------------
// Pass B + Layer 1 fused: one block (512 thr) per 256-node bucket.
//   1. LDS counting sort of the bucket's edges -> ssrc, rowpair, esrc
//   2. layer-1 x-gather straight from LDS ssrc (node-per-thread-pair)
//   3. linear phase: feat-per-thread, weights hoisted to registers,
//      broadcast float4 LDS reads of the per-node mean/self rows -> bf16 z
// Static LDS = 61.5 KB (raw region reused for smx/spart after the sort).
// ---------------------------------------------------------------------------
__global__ __launch_bounds__(512) void bucket_layer1(
        const unsigned int* __restrict__ ebin,
        const int* __restrict__ gcur,
        const float* __restrict__ x,
        const float* __restrict__ W1l,
        const float* __restrict__ b1,
        const float* __restrict__ W1r,
        int2* __restrict__ rowpair,
        unsigned short* __restrict__ esrc,
        unsigned short* __restrict__ z) {
    __shared__ int raw[BCAP];                  // 36864 B (aliased below)
    __shared__ unsigned short ssrc[BCAP];      // 18432 B
    __shared__ int sdeg[256];
    __shared__ int sstart[256];
    __shared__ int scur[256];
    __shared__ int wsum[4];
    __shared__ float sW1l[IN_DIM * H];
    __shared__ float sW1r[IN_DIM * H];
    float* smx   = (float*)raw;                // [256][16]: mean 0..5, self 6..11
    float* spart = (float*)raw + 4096;         // [256][6] half-1 partials

    int t = threadIdx.x;
    int lane = t & 63, w = t >> 6;
    int b = blockIdx.x;
    int base = b << 8;
    int nn = min(256, N_NODES - base);         // last bucket has 80 nodes
    int ebase = b * BCAP;
    int cnt = min(gcur[b], BCAP);

    if (t < 256) sdeg[t] = 0;
    for (int i = t; i < IN_DIM * H; i += 512) { sW1l[i] = W1l[i]; sW1r[i] = W1r[i]; }
    for (int i = t; i < cnt; i += 512) raw[i] = (int)ebin[ebase + i];
    __syncthreads();
    for (int i = t; i < cnt; i += 512) atomicAdd(&sdeg[raw[i] & 0xff], 1);
    __syncthreads();
    int v = 0, s = 0;
    if (t < 256) {                              // waves 0..3: scan of 256 bins
        v = sdeg[t]; s = v;
#pragma unroll
        for (int off = 1; off < 64; off <<= 1) {
            int u = __shfl_up(s, off);
            if (lane >= off) s += u;
        }
        if (lane == 63) wsum[w] = s;
    }
    __syncthreads();
    if (t < 256) {
        int woff = 0;
        for (int k = 0; k < w; k++) woff += wsum[k];
        int excl = s - v + woff;                // bucket-local exclusive prefix
        sstart[t] = excl;
        scur[t] = excl;
        if (t < nn) rowpair[base + t] = make_int2(ebase + excl, ebase + excl + v);
    }
    __syncthreads();
    for (int i = t; i < cnt; i += 512) {        // in-LDS scatter (sort)
        int p = raw[i];
        int pos = atomicAdd(&scur[p & 0xff], 1);
        ssrc[pos] = (unsigned short)((unsigned)p >> 16);
    }
    __syncthreads();
    // raw[] dead from here on: smx/spart alias it.
    for (int i = t; i < cnt; i += 512)          // coalesced esrc write (layer2)
        esrc[ebase + i] = ssrc[i];
    for (int i = t; i < nn * IN_DIM; i += 512) {  // stage self x rows (contig)
        int node = i / 6, k = i - node * 6;
        smx[node * 16 + 6 + k] = x[(size_t)base * IN_DIM + i];
    }

    // ---- layer-1 gather: node-per-thread-pair, each edge read once ----
    int node = t & 255, half = t >> 8;
    float a0 = 0.f, a1 = 0.f, a2 = 0.f, a3 = 0.f, a4 = 0.f, a5 = 0.f;
    int deg = 0, st = 0;
    if (node < nn) { deg = sdeg[node]; st = sstart[node]; }
    for (int i = st + half; i < st + deg; i += 2) {
        int src = ssrc[i];
        const float2* xs = (const float2*)(x + (size_t)src * IN_DIM);
        float2 p0 = xs[0], p1 = xs[1], p2 = xs[2];
        a0 += p0.x; a1 += p0.y; a2 += p1.x;
        a3 += p1.y; a4 += p2.x; a5 += p2.y;
    }
    if (half == 1 && node < nn) {
        spart[node * 6 + 0] = a0; spart[node * 6 + 1] = a1;
        spart[node * 6 + 2] = a2; spart[node * 6 + 3] = a3;
        spart[node * 6 + 4] = a4; spart[node * 6 + 5] = a5;
    }
    __syncthreads();
    if (half == 0 && node < nn) {
        float inv = 1.0f / fmaxf((float)deg, 1.0f);
        smx[node * 16 + 0] = (a0 + spart[node * 6 + 0]) * inv;
        smx[node * 16 + 1] = (a1 + spart[node * 6 + 1]) * inv;
        smx[node * 16 + 2] = (a2 + spart[node * 6 + 2]) * inv;
        smx[node * 16 + 3] = (a3 + spart[node * 6 + 3]) * inv;
        smx[node * 16 + 4] = (a4 + spart[node * 6 + 4]) * inv;
        smx[node * 16 + 5] = (a5 + spart[node * 6 + 5]) * inv;
    }
    __syncthreads();

    // ---- layer-1 linear: feat-per-thread, weights in registers ----
    int feat = t & 63, ng = t >> 6;             // 8 node-groups
    float wl[IN_DIM], wr[IN_DIM];
#pragma unroll
    for (int k = 0; k < IN_DIM; k++) { wl[k] = sW1l[k * H + feat]; wr[k] = sW1r[k * H + feat]; }
    float bias = b1[feat];
    for (int nb = ng; nb < nn; nb += 8) {
        const float4* row = (const float4*)&smx[nb * 16];  // broadcast reads
        float4 r0 = row[0], r1 = row[1], r2 = row[2];
        float acc = bias;
        acc += r0.x * wl[0] + r0.y * wl[1] + r0.z * wl[2]
             + r0.w * wl[3] + r1.x * wl[4] + r1.y * wl[5];
        acc += r1.z * wr[0] + r1.w * wr[1] + r2.x * wr[2]
             + r2.y * wr[3] + r2.z * wr[4] + r2.w * wr[5];
        z[(size_t)(base + nb) * H + feat] = f2bf(fmaxf(acc, 0.0f));
    }
}

// ---------------------------------------------------------------------------
// Layer 2, MFMA epilogue: 512 thr / 8 waves / 32 nodes per block (grid 1563,
// LDS 27.6KB -> 4 blocks/CU = 32 waves/CU, up from round-9's 24).
// Gather: wave w -> nodes w*4..w*4+3 (proven 4-group ushort4 pattern).
// MFMA: wave w -> nodes [16*(w>>2), +16) x feats [16*(w&3), +16).
// ---------------------------------------------------------------------------
__global__ __launch_bounds__(512) void layer2_mfma(
        const unsigned short* __restrict__ zin,
        const int2* __restrict__ rowpair,
        const unsigned short* __restrict__ esrc,
        const unsigned short* __restrict__ Wlt,
        const float* __restrict__ b2,
        const unsigned short* __restrict__ Wrt,
        float* __restrict__ out) {
    typedef short bf16x8 __attribute__((ext_vector_type(8)));
    typedef float f32x4 __attribute__((ext_vector_type(4)));
    __shared__ __attribute__((aligned(16))) unsigned short smean[32 * L2PAD];
    __shared__ __attribute__((aligned(16))) unsigned short szl[32 * L2PAD];
    __shared__ __attribute__((aligned(16))) unsigned short sWl[64 * L2PAD];
    __shared__ __attribute__((aligned(16))) unsigned short sWr[64 * L2PAD];

    int t = threadIdx.x;
    int w = t >> 6, lane = t & 63;
    int g = lane >> 4, lg = lane & 15;
    int n0 = blockIdx.x * 32;

    // stage pre-transposed bf16 weights (k-consecutive: conflict-free)
    {
        const ushort4* wl4 = (const ushort4*)Wlt;
        const ushort4* wr4 = (const ushort4*)Wrt;
        for (int qi = t; qi < H * H / 4; qi += 512) {
            int f = qi >> 4, kq = qi & 15;
            *(ushort4*)&sWl[f * L2PAD + kq * 4] = wl4[qi];
            *(ushort4*)&sWr[f * L2PAD + kq * 4] = wr4[qi];
        }
    }

    // ---- gather phase: wave w -> nodes w*4 .. w*4+3 ----
    for (int q = 0; q < 4; q++) {
        int ln = w * 4 + q;
        int n = n0 + ln;
        bool valid = (n < N_NODES);
        int r0 = 0, r1 = 0;
        if (valid) { int2 rp = rowpair[n]; r0 = rp.x; r1 = rp.y; }
        float4 acc = make_float4(0.f, 0.f, 0.f, 0.f);
        for (int base = r0; base < r1; base += 64) {
            int ii = base + lane;
            int idx = (ii < r1) ? (int)esrc[ii] : N_NODES;   // zero row
            int rem = r1 - base;                             // wave-uniform
#pragma unroll 1
            for (int c = 0; c < 64; c += 16) {
                if (c >= rem) break;                         // wave-uniform
#pragma unroll
                for (int tt = 0; tt < 4; tt++) {
                    int j = c + tt * 4 + g;
                    int s = __shfl(idx, j);
                    const ushort4* zr = (const ushort4*)(zin + (size_t)s * H);
                    ushort4 vv = zr[lg];
                    acc.x += bf2f(vv.x); acc.y += bf2f(vv.y);
                    acc.z += bf2f(vv.z); acc.w += bf2f(vv.w);
                }
            }
        }
#pragma unroll
        for (int off = 16; off < 64; off <<= 1) {
            acc.x += __shfl_xor(acc.x, off);
            acc.y += __shfl_xor(acc.y, off);
            acc.z += __shfl_xor(acc.z, off);
            acc.w += __shfl_xor(acc.w, off);
        }
        float inv = 1.0f / fmaxf((float)(r1 - r0), 1.0f);
        if (g == 0) {
            ushort4 mb;
            mb.x = f2bf(acc.x * inv); mb.y = f2bf(acc.y * inv);
            mb.z = f2bf(acc.z * inv); mb.w = f2bf(acc.w * inv);
            *(ushort4*)&smean[ln * L2PAD + lg * 4] = mb;
        }
        int nz = valid ? n : N_NODES;                        // zero row for pad
        szl[ln * L2PAD + lane] = zin[(size_t)nz * H + lane];
    }
    __syncthreads();

    // ---- MFMA phase: wave w -> nodes [16*(w>>2), +16) x feats [16*(w&3), +16)
    int nb = w >> 2, fb = w & 3;
    f32x4 acc = {0.f, 0.f, 0.f, 0.f};
#pragma unroll
    for (int ks = 0; ks < 2; ks++) {
        int ko = ks * 32 + g * 8;
        bf16x8 aM = *(const bf16x8*)&smean[(nb * 16 + lg) * L2PAD + ko];
        bf16x8 aZ = *(const bf16x8*)&szl[(nb * 16 + lg) * L2PAD + ko];
        bf16x8 bL = *(const bf16x8*)&sWl[(fb * 16 + lg) * L2PAD + ko];
        bf16x8 bR = *(const bf16x8*)&sWr[(fb * 16 + lg) * L2PAD + ko];
        acc = __builtin_amdgcn_mfma_f32_16x16x32_bf16(aM, bL, acc, 0, 0, 0);
        acc = __builtin_amdgcn_mfma_f32_16x16x32_bf16(aZ, bR, acc, 0, 0, 0);
    }
    float bias = b2[fb * 16 + lg];
#pragma unroll
    for (int r = 0; r < 4; r++) {
        int node = n0 + nb * 16 + g * 4 + r;
        if (node < N_NODES)
            out[(size_t)node * H + fb * 16 + lg] = acc[r] + bias;
    }
}

// ---------------------------------------------------------------------------
extern "C" void kernel_launch(void* const* d_in, const int* in_sizes, int n_in,
                              void* d_out, int out_size, void* d_ws, size_t ws_size,
                              hipStream_t stream) {
    const float* x   = (const float*)d_in[0];
    const int*   ei  = (const int*)d_in[1];   // [2, N_EDGES]
    const float* W1l = (const float*)d_in[2];
    const float* b1  = (const float*)d_in[3];
    const float* W1r = (const float*)d_in[4];
    const float* W2l = (const float*)d_in[5];
    const float* b2  = (const float*)d_in[6];
    const float* W2r = (const float*)d_in[7];
    float* out = (float*)d_out;

    // Workspace layout (keeps 16B alignment for ebin/esrc/z/weights):
    int* gcur = (int*)d_ws;                              // 196 (+pad to 208)
    int2* rowpair = (int2*)(gcur + 208);                 // 50000 int2
    unsigned int*   ebin = (unsigned int*)(rowpair + N_NODES);  // 196*9216 u32
    unsigned short* esrc = (unsigned short*)(ebin + (size_t)NBUCKET * BCAP);
    unsigned short* z    = esrc + (size_t)NBUCKET * BCAP;  // (N_NODES+1)*H bf16
    unsigned short* Wlt  = z + (size_t)(N_NODES + 1) * H;  // 4096 bf16
    unsigned short* Wrt  = Wlt + H * H;                    // 4096 bf16

    hipMemsetAsync(gcur, 0, NBUCKET * sizeof(int), stream);

    // CSR build + layer1 (fused), then layer2
    scatter_bucketed<<<NBLK + 1, 256, 0, stream>>>(ei, gcur, ebin,
                                                   W2l, W2r, Wlt, Wrt, z);
    bucket_layer1<<<NBUCKET, 512, 0, stream>>>(ebin, gcur, x, W1l, b1, W1r,
                                               rowpair, esrc, z);
    layer2_mfma<<<(N_NODES + 31) / 32, 512, 0, stream>>>(z, rowpair, esrc,
                                                         Wlt, b2, Wrt, out);
}

// Round 12
// 149.903 us; speedup vs baseline: 1.0567x; 1.0198x over previous
//
#include <hip/hip_runtime.h>

#define N_NODES 50000
#define N_EDGES 1600000
#define IN_DIM 6
#define H 64

#define NBUCKET 196            // dst >> 8  (256 nodes per bucket)
#define NBLK 196               // edge chunks
#define EPB 8192               // edges per chunk (196*8192 >= 1.6M)
#define BCAP 9216              // bucket capacity: mean 8163, sd ~90 -> +11.6 sd

#define L2PAD 72               // padded LDS row stride (bf16) = 144B

// bf16 helpers (storage-only; all math in fp32)
__device__ __forceinline__ float bf2f(unsigned short u) {
    return __uint_as_float(((unsigned int)u) << 16);
}
__device__ __forceinline__ unsigned short f2bf(float f) {
    unsigned int u = __float_as_uint(f);
    u += 0x7fffu + ((u >> 16) & 1u);   // round-to-nearest-even
    return (unsigned short)(u >> 16);
}

// ---------------------------------------------------------------------------
// Pass A (fused): stage edges in LDS, LDS histogram, reserve bucket ranges
// via ONE global atomicAdd per (block,bucket), scatter from LDS.
// 196 chunks of 8192: per-(block,bucket) ebin runs ~42 edges (~168B) — keeps
// scatter writes mostly-full-line (round-10 showed smaller runs regress).
// 512 threads (round-12: was 256) for latency hiding; layouts unchanged.
// Extra block NBLK does the W2 transpose prep + zeroes z's dummy row.
// ---------------------------------------------------------------------------
__global__ __launch_bounds__(512) void scatter_bucketed(
        const int* __restrict__ ei,
        int* __restrict__ gcur,
        unsigned int* __restrict__ ebin,
        const float* __restrict__ W2l,
        const float* __restrict__ W2r,
        unsigned short* __restrict__ Wlt,
        unsigned short* __restrict__ Wrt,
        unsigned short* __restrict__ z) {
    int t = threadIdx.x;
    if (blockIdx.x == NBLK) {                  // w2prep + z zero-row block
        for (int i = t; i < H * H; i += 512) {
            int k = i >> 6, f = i & 63;
            Wlt[f * H + k] = f2bf(W2l[i]);
            Wrt[f * H + k] = f2bf(W2r[i]);
        }
        if (t < H) z[(size_t)N_NODES * H + t] = 0;
        return;
    }
    __shared__ unsigned int sedge[EPB];        // 32 KB staged edges
    __shared__ int hist[NBUCKET];
    __shared__ int cur[NBUCKET];
    for (int i = t; i < NBUCKET; i += 512) hist[i] = 0;
    __syncthreads();
    int e0 = blockIdx.x * EPB;
    int cnt = min(EPB, N_EDGES - e0);          // multiple of 4
    const int4* s4 = (const int4*)(ei + e0);
    const int4* d4 = (const int4*)(ei + N_EDGES + e0);
    for (int k = t; k * 4 < cnt; k += 512) {
        int4 sv = s4[k];
        int4 dv = d4[k];
        sedge[k * 4 + 0] = ((unsigned)sv.x << 16) | (unsigned)dv.x;
        sedge[k * 4 + 1] = ((unsigned)sv.y << 16) | (unsigned)dv.y;
        sedge[k * 4 + 2] = ((unsigned)sv.z << 16) | (unsigned)dv.z;
        sedge[k * 4 + 3] = ((unsigned)sv.w << 16) | (unsigned)dv.w;
        atomicAdd(&hist[dv.x >> 8], 1);
        atomicAdd(&hist[dv.y >> 8], 1);
        atomicAdd(&hist[dv.z >> 8], 1);
        atomicAdd(&hist[dv.w >> 8], 1);
    }
    __syncthreads();
    for (int i = t; i < NBUCKET; i += 512)
        cur[i] = atomicAdd(&gcur[i], hist[i]);
    __syncthreads();
    for (int k = t; k * 4 < cnt; k += 512) {
#pragma unroll
        for (int j = 0; j < 4; j++) {
            unsigned int p = sedge[k * 4 + j];
            int b = (int)(p & 0xffffu) >> 8;
            int pos = atomicAdd(&cur[b], 1);
            if (pos < BCAP) ebin[(size_t)b * BCAP + pos] = p;
        }
    }
}

// ---------------------------------------------------------------------------
// Pass B + Layer 1 fused: one block (1024 thr, round-12: was 512) per
// 256-node bucket.
//   1. LDS counting sort of the bucket's edges -> ssrc, rowpair, esrc
//   2. layer-1 x-gather straight from LDS ssrc (4 threads per node)
//   3. linear phase: feat-per-thread, weights hoisted to registers,
//      broadcast float4 LDS reads of the per-node mean/self rows -> bf16 z
// Static LDS = 61.5 KB (raw region reused for smx/spart after the sort).
// ---------------------------------------------------------------------------
__global__ __launch_bounds__(1024) void bucket_layer1(
        const unsigned int* __restrict__ ebin,
        const int* __restrict__ gcur,
        const float* __restrict__ x,
        const float* __restrict__ W1l,
        const float* __restrict__ b1,
        const float* __restrict__ W1r,
        int2* __restrict__ rowpair,
        unsigned short* __restrict__ esrc,
        unsigned short* __restrict__ z) {
    __shared__ int raw[BCAP];                  // 36864 B (aliased below)
    __shared__ unsigned short ssrc[BCAP];      // 18432 B
    __shared__ int sdeg[256];
    __shared__ int sstart[256];
    __shared__ int scur[256];
    __shared__ int wsum[4];
    __shared__ float sW1l[IN_DIM * H];
    __shared__ float sW1r[IN_DIM * H];
    float* smx   = (float*)raw;                // [256][16]: mean 0..5, self 6..11
    float* spart = (float*)raw + 4096;         // [3][256][6] partials (q=1..3)

    int t = threadIdx.x;
    int lane = t & 63, w = t >> 6;
    int b = blockIdx.x;
    int base = b << 8;
    int nn = min(256, N_NODES - base);         // last bucket has 80 nodes
    int ebase = b * BCAP;
    int cnt = min(gcur[b], BCAP);

    if (t < 256) sdeg[t] = 0;
    if (t < IN_DIM * H) { sW1l[t] = W1l[t]; sW1r[t] = W1r[t]; }
    for (int i = t; i < cnt; i += 1024) raw[i] = (int)ebin[ebase + i];
    __syncthreads();
    for (int i = t; i < cnt; i += 1024) atomicAdd(&sdeg[raw[i] & 0xff], 1);
    __syncthreads();
    int v = 0, s = 0;
    if (t < 256) {                              // waves 0..3: scan of 256 bins
        v = sdeg[t]; s = v;
#pragma unroll
        for (int off = 1; off < 64; off <<= 1) {
            int u = __shfl_up(s, off);
            if (lane >= off) s += u;
        }
        if (lane == 63) wsum[w] = s;
    }
    __syncthreads();
    if (t < 256) {
        int woff = 0;
        for (int k = 0; k < w; k++) woff += wsum[k];
        int excl = s - v + woff;                // bucket-local exclusive prefix
        sstart[t] = excl;
        scur[t] = excl;
        if (t < nn) rowpair[base + t] = make_int2(ebase + excl, ebase + excl + v);
    }
    __syncthreads();
    for (int i = t; i < cnt; i += 1024) {       // in-LDS scatter (sort)
        int p = raw[i];
        int pos = atomicAdd(&scur[p & 0xff], 1);
        ssrc[pos] = (unsigned short)((unsigned)p >> 16);
    }
    __syncthreads();
    // raw[] dead from here on: smx/spart alias it.
    for (int i = t; i < cnt; i += 1024)         // coalesced esrc write (layer2)
        esrc[ebase + i] = ssrc[i];
    for (int i = t; i < nn * IN_DIM; i += 1024) {  // stage self x rows (contig)
        int node = i / 6, k = i - node * 6;
        smx[node * 16 + 6 + k] = x[(size_t)base * IN_DIM + i];
    }

    // ---- layer-1 gather: 4 threads per node, each edge read once ----
    int node = t & 255, q = t >> 8;             // q in 0..3
    float a0 = 0.f, a1 = 0.f, a2 = 0.f, a3 = 0.f, a4 = 0.f, a5 = 0.f;
    int deg = 0, st = 0;
    if (node < nn) { deg = sdeg[node]; st = sstart[node]; }
    for (int i = st + q; i < st + deg; i += 4) {
        int src = ssrc[i];
        const float2* xs = (const float2*)(x + (size_t)src * IN_DIM);
        float2 p0 = xs[0], p1 = xs[1], p2 = xs[2];
        a0 += p0.x; a1 += p0.y; a2 += p1.x;
        a3 += p1.y; a4 += p2.x; a5 += p2.y;
    }
    if (q > 0 && node < nn) {
        float* sp = &spart[(q - 1) * (256 * 6) + node * 6];
        sp[0] = a0; sp[1] = a1; sp[2] = a2; sp[3] = a3; sp[4] = a4; sp[5] = a5;
    }
    __syncthreads();
    if (q == 0 && node < nn) {
        float inv = 1.0f / fmaxf((float)deg, 1.0f);
        const float* p1p = &spart[0 * (256 * 6) + node * 6];
        const float* p2p = &spart[1 * (256 * 6) + node * 6];
        const float* p3p = &spart[2 * (256 * 6) + node * 6];
        smx[node * 16 + 0] = (a0 + p1p[0] + p2p[0] + p3p[0]) * inv;
        smx[node * 16 + 1] = (a1 + p1p[1] + p2p[1] + p3p[1]) * inv;
        smx[node * 16 + 2] = (a2 + p1p[2] + p2p[2] + p3p[2]) * inv;
        smx[node * 16 + 3] = (a3 + p1p[3] + p2p[3] + p3p[3]) * inv;
        smx[node * 16 + 4] = (a4 + p1p[4] + p2p[4] + p3p[4]) * inv;
        smx[node * 16 + 5] = (a5 + p1p[5] + p2p[5] + p3p[5]) * inv;
    }
    __syncthreads();

    // ---- layer-1 linear: feat-per-thread, weights in registers ----
    int feat = t & 63, ng = t >> 6;             // 16 node-groups
    float wl[IN_DIM], wr[IN_DIM];
#pragma unroll
    for (int k = 0; k < IN_DIM; k++) { wl[k] = sW1l[k * H + feat]; wr[k] = sW1r[k * H + feat]; }
    float bias = b1[feat];
    for (int nb = ng; nb < nn; nb += 16) {
        const float4* row = (const float4*)&smx[nb * 16];  // broadcast reads
        float4 r0 = row[0], r1 = row[1], r2 = row[2];
        float acc = bias;
        acc += r0.x * wl[0] + r0.y * wl[1] + r0.z * wl[2]
             + r0.w * wl[3] + r1.x * wl[4] + r1.y * wl[5];
        acc += r1.z * wr[0] + r1.w * wr[1] + r2.x * wr[2]
             + r2.y * wr[3] + r2.z * wr[4] + r2.w * wr[5];
        z[(size_t)(base + nb) * H + feat] = f2bf(fmaxf(acc, 0.0f));
    }
}

// ---------------------------------------------------------------------------
// Layer 2, MFMA epilogue: 512 thr / 8 waves / 32 nodes per block (grid 1563).
// Gather: wave w -> nodes w*4..w*4+3 (proven 4-group ushort4 pattern).
// MFMA: wave w -> nodes [16*(w>>2), +16) x feats [16*(w&3), +16).
// ---------------------------------------------------------------------------
__global__ __launch_bounds__(512) void layer2_mfma(
        const unsigned short* __restrict__ zin,
        const int2* __restrict__ rowpair,
        const unsigned short* __restrict__ esrc,
        const unsigned short* __restrict__ Wlt,
        const float* __restrict__ b2,
        const unsigned short* __restrict__ Wrt,
        float* __restrict__ out) {
    typedef short bf16x8 __attribute__((ext_vector_type(8)));
    typedef float f32x4 __attribute__((ext_vector_type(4)));
    __shared__ __attribute__((aligned(16))) unsigned short smean[32 * L2PAD];
    __shared__ __attribute__((aligned(16))) unsigned short szl[32 * L2PAD];
    __shared__ __attribute__((aligned(16))) unsigned short sWl[64 * L2PAD];
    __shared__ __attribute__((aligned(16))) unsigned short sWr[64 * L2PAD];

    int t = threadIdx.x;
    int w = t >> 6, lane = t & 63;
    int g = lane >> 4, lg = lane & 15;
    int n0 = blockIdx.x * 32;

    // stage pre-transposed bf16 weights (k-consecutive: conflict-free)
    {
        const ushort4* wl4 = (const ushort4*)Wlt;
        const ushort4* wr4 = (const ushort4*)Wrt;
        for (int qi = t; qi < H * H / 4; qi += 512) {
            int f = qi >> 4, kq = qi & 15;
            *(ushort4*)&sWl[f * L2PAD + kq * 4] = wl4[qi];
            *(ushort4*)&sWr[f * L2PAD + kq * 4] = wr4[qi];
        }
    }

    // ---- gather phase: wave w -> nodes w*4 .. w*4+3 ----
    for (int q = 0; q < 4; q++) {
        int ln = w * 4 + q;
        int n = n0 + ln;
        bool valid = (n < N_NODES);
        int r0 = 0, r1 = 0;
        if (valid) { int2 rp = rowpair[n]; r0 = rp.x; r1 = rp.y; }
        float4 acc = make_float4(0.f, 0.f, 0.f, 0.f);
        for (int base = r0; base < r1; base += 64) {
            int ii = base + lane;
            int idx = (ii < r1) ? (int)esrc[ii] : N_NODES;   // zero row
            int rem = r1 - base;                             // wave-uniform
#pragma unroll 1
            for (int c = 0; c < 64; c += 16) {
                if (c >= rem) break;                         // wave-uniform
#pragma unroll
                for (int tt = 0; tt < 4; tt++) {
                    int j = c + tt * 4 + g;
                    int s = __shfl(idx, j);
                    const ushort4* zr = (const ushort4*)(zin + (size_t)s * H);
                    ushort4 vv = zr[lg];
                    acc.x += bf2f(vv.x); acc.y += bf2f(vv.y);
                    acc.z += bf2f(vv.z); acc.w += bf2f(vv.w);
                }
            }
        }
#pragma unroll
        for (int off = 16; off < 64; off <<= 1) {
            acc.x += __shfl_xor(acc.x, off);
            acc.y += __shfl_xor(acc.y, off);
            acc.z += __shfl_xor(acc.z, off);
            acc.w += __shfl_xor(acc.w, off);
        }
        float inv = 1.0f / fmaxf((float)(r1 - r0), 1.0f);
        if (g == 0) {
            ushort4 mb;
            mb.x = f2bf(acc.x * inv); mb.y = f2bf(acc.y * inv);
            mb.z = f2bf(acc.z * inv); mb.w = f2bf(acc.w * inv);
            *(ushort4*)&smean[ln * L2PAD + lg * 4] = mb;
        }
        int nz = valid ? n : N_NODES;                        // zero row for pad
        szl[ln * L2PAD + lane] = zin[(size_t)nz * H + lane];
    }
    __syncthreads();

    // ---- MFMA phase: wave w -> nodes [16*(w>>2), +16) x feats [16*(w&3), +16)
    int nb = w >> 2, fb = w & 3;
    f32x4 acc = {0.f, 0.f, 0.f, 0.f};
#pragma unroll
    for (int ks = 0; ks < 2; ks++) {
        int ko = ks * 32 + g * 8;
        bf16x8 aM = *(const bf16x8*)&smean[(nb * 16 + lg) * L2PAD + ko];
        bf16x8 aZ = *(const bf16x8*)&szl[(nb * 16 + lg) * L2PAD + ko];
        bf16x8 bL = *(const bf16x8*)&sWl[(fb * 16 + lg) * L2PAD + ko];
        bf16x8 bR = *(const bf16x8*)&sWr[(fb * 16 + lg) * L2PAD + ko];
        acc = __builtin_amdgcn_mfma_f32_16x16x32_bf16(aM, bL, acc, 0, 0, 0);
        acc = __builtin_amdgcn_mfma_f32_16x16x32_bf16(aZ, bR, acc, 0, 0, 0);
    }
    float bias = b2[fb * 16 + lg];
#pragma unroll
    for (int r = 0; r < 4; r++) {
        int node = n0 + nb * 16 + g * 4 + r;
        if (node < N_NODES)
            out[(size_t)node * H + fb * 16 + lg] = acc[r] + bias;
    }
}

// ---------------------------------------------------------------------------
extern "C" void kernel_launch(void* const* d_in, const int* in_sizes, int n_in,
                              void* d_out, int out_size, void* d_ws, size_t ws_size,
                              hipStream_t stream) {
    const float* x   = (const float*)d_in[0];
    const int*   ei  = (const int*)d_in[1];   // [2, N_EDGES]
    const float* W1l = (const float*)d_in[2];
    const float* b1  = (const float*)d_in[3];
    const float* W1r = (const float*)d_in[4];
    const float* W2l = (const float*)d_in[5];
    const float* b2  = (const float*)d_in[6];
    const float* W2r = (const float*)d_in[7];
    float* out = (float*)d_out;

    // Workspace layout (keeps 16B alignment for ebin/esrc/z/weights):
    int* gcur = (int*)d_ws;                              // 196 (+pad to 208)
    int2* rowpair = (int2*)(gcur + 208);                 // 50000 int2
    unsigned int*   ebin = (unsigned int*)(rowpair + N_NODES);  // 196*9216 u32
    unsigned short* esrc = (unsigned short*)(ebin + (size_t)NBUCKET * BCAP);
    unsigned short* z    = esrc + (size_t)NBUCKET * BCAP;  // (N_NODES+1)*H bf16
    unsigned short* Wlt  = z + (size_t)(N_NODES + 1) * H;  // 4096 bf16
    unsigned short* Wrt  = Wlt + H * H;                    // 4096 bf16

    hipMemsetAsync(gcur, 0, NBUCKET * sizeof(int), stream);

    // CSR build + layer1 (fused), then layer2
    scatter_bucketed<<<NBLK + 1, 512, 0, stream>>>(ei, gcur, ebin,
                                                   W2l, W2r, Wlt, Wrt, z);
    bucket_layer1<<<NBUCKET, 1024, 0, stream>>>(ebin, gcur, x, W1l, b1, W1r,
                                                rowpair, esrc, z);
    layer2_mfma<<<(N_NODES + 31) / 32, 512, 0, stream>>>(z, rowpair, esrc,
                                                         Wlt, b2, Wrt, out);
}